// Round 4
// baseline (13200.401 us; speedup 1.0000x reference)
//
#include <hip/hip_runtime.h>
#include <math.h>

#define NB 4
#define NE 64
#define BE 256          // NB*NE
#define LAT 256
#define NC 512          // channels == window
#define NT 128          // n_frames
#define NDEF 65536      // NC*NT
#define NIMP 4096
#define NF 16           // impulse frames
#define EPSN 1e-8f
#define SPB 8           // sequences per scan block
#define NSCAN 32        // scan blocks (BE/SPB)

typedef unsigned short ushort8 __attribute__((ext_vector_type(8)));
typedef short short8v __attribute__((ext_vector_type(8)));
typedef float f32x4 __attribute__((ext_vector_type(4)));

__device__ __forceinline__ unsigned short f2bf(float f) {
  const unsigned u = __float_as_uint(f);
  return (unsigned short)((u + 0x7FFFu + ((u >> 16) & 1u)) >> 16);  // RNE
}

// ---------------------------------------------------------------------------
// block-wide reduction: each of 512 threads contributes v[NR]; result (sum)
// broadcast to all threads via shared out[NR]. red is shared scratch [8][8].
// ---------------------------------------------------------------------------
template <int NR>
__device__ __forceinline__ void blk_reduce(const float* v, float* out,
                                           float (*red)[8]) {
  const int tid = threadIdx.x, wave = tid >> 6, lane = tid & 63;
  float s[NR];
#pragma unroll
  for (int i = 0; i < NR; ++i) s[i] = v[i];
#pragma unroll
  for (int off = 32; off; off >>= 1) {
#pragma unroll
    for (int i = 0; i < NR; ++i) s[i] += __shfl_down(s[i], off);
  }
  if (lane == 0) {
#pragma unroll
    for (int i = 0; i < NR; ++i) red[wave][i] = s[i];
  }
  __syncthreads();
  if (tid < NR) {
    float acc = 0.f;
#pragma unroll
    for (int w = 0; w < 8; ++w) acc += red[w][tid];
    out[tid] = acc;
  }
  __syncthreads();
}

// ---------------------------------------------------------------------------
// K0: swizzle Ws_lat (4 x [512 k][512 n] f32) into MFMA B-fragment order bf16:
// Wmf[((layer*32+nt)*16+kt)*64 + lane][j] = bf16(W[layer][kt*32+(lane>>4)*8+j]
//                                                       [nt*16+(lane&15)])
// grid 2048 (= 4*32*16), block 64.
// ---------------------------------------------------------------------------
__global__ __launch_bounds__(64) void k_cvt(const float* __restrict__ W,
                                            unsigned short* __restrict__ Wmf) {
  const int lane = threadIdx.x;
  const int gg = blockIdx.x;  // (layer*32 + nt)*16 + kt
  const int kt = gg & 15;
  const int lnt = gg >> 4;
  const int layer = lnt >> 5, nt = lnt & 31;
  const int col = nt * 16 + (lane & 15);
  const int k0 = kt * 32 + (lane >> 4) * 8;
  ushort8 o;
#pragma unroll
  for (int j = 0; j < 8; ++j)
    o[j] = f2bf(W[((size_t)layer * NC + k0 + j) * NC + col]);
  *reinterpret_cast<ushort8*>(Wmf + ((size_t)gg * 64 + lane) * 8) = o;
}

// ---------------------------------------------------------------------------
// K1: deform = embedding @ W_def + b_def      (256 x 256) @ (256 x 65536)
// ---------------------------------------------------------------------------
__global__ __launch_bounds__(256) void k_deform(
    const float* __restrict__ emb, const float* __restrict__ Wd,
    const float* __restrict__ bd, float* __restrict__ deform) {
  __shared__ float As[32][LAT];
  const int tid = threadIdx.x;
  const int c = blockIdx.x * 256 + tid;
  const int m0 = blockIdx.y * 32;
  for (int i = 0; i < 32; ++i) As[i][tid] = emb[(m0 + i) * LAT + tid];
  __syncthreads();
  float acc[32];
#pragma unroll
  for (int i = 0; i < 32; ++i) acc[i] = 0.f;
  for (int k = 0; k < LAT; k += 4) {
    const float w0 = Wd[(size_t)(k + 0) * NDEF + c];
    const float w1 = Wd[(size_t)(k + 1) * NDEF + c];
    const float w2 = Wd[(size_t)(k + 2) * NDEF + c];
    const float w3 = Wd[(size_t)(k + 3) * NDEF + c];
#pragma unroll
    for (int i = 0; i < 32; ++i) {
      const float4 a = *reinterpret_cast<const float4*>(&As[i][k]);
      acc[i] = fmaf(a.x, w0, acc[i]);
      acc[i] = fmaf(a.y, w1, acc[i]);
      acc[i] = fmaf(a.z, w2, acc[i]);
      acc[i] = fmaf(a.w, w3, acc[i]);
    }
  }
  const float bv = bd[c];
  for (int i = 0; i < 32; ++i)
    deform[(size_t)(m0 + i) * NDEF + c] = acc[i] + bv;
}

// ---------------------------------------------------------------------------
// K2: per-(be,t) rows of deform: unit_norm over channel dim, then
//   weights = x @ W_w + b_w ; biases = x @ W_b + b_b ; leak = sigmoid path.
// ---------------------------------------------------------------------------
__global__ __launch_bounds__(512) void k_wb(
    const float* __restrict__ deform, const float* __restrict__ Ww,
    const float* __restrict__ bw, const float* __restrict__ Wb,
    const float* __restrict__ bb, const float* __restrict__ Wl,
    const float* __restrict__ bl, float* __restrict__ weights,
    float* __restrict__ biases, float* __restrict__ leak) {
  __shared__ float xs[16][NC];
  __shared__ float rno[16], lks[16];
  const int tid = threadIdx.x;
  const int wave = tid >> 6, lane = tid & 63;
  const int be = blockIdx.x >> 3;
  const int t0 = (blockIdx.x & 7) * 16;
  const float* dbase = deform + (size_t)be * NDEF;
  for (int i = 0; i < 16; ++i)
    xs[i][tid] = dbase[(size_t)tid * NT + t0 + i];
  __syncthreads();
  for (int f = wave; f < 16; f += 8) {
    float s = 0.f;
#pragma unroll
    for (int j = 0; j < 8; ++j) {
      const float v = xs[f][lane + 64 * j];
      s = fmaf(v, v, s);
    }
#pragma unroll
    for (int off = 32; off; off >>= 1) s += __shfl_down(s, off);
    if (lane == 0) rno[f] = sqrtf(s);
  }
  __syncthreads();
#pragma unroll
  for (int i = 0; i < 16; ++i) xs[i][tid] = xs[i][tid] / (rno[i] + EPSN);
  __syncthreads();
  for (int f = wave; f < 16; f += 8) {
    float s = 0.f;
#pragma unroll
    for (int j = 0; j < 8; ++j)
      s = fmaf(xs[f][lane + 64 * j], Wl[lane + 64 * j], s);
#pragma unroll
    for (int off = 32; off; off >>= 1) s += __shfl_down(s, off);
    if (lane == 0) lks[f] = s;
  }
  __syncthreads();
  if (tid < 16) {
    const float v = lks[tid] + bl[0];
    leak[(size_t)be * NT + t0 + tid] = 0.1f + 0.98f / (1.f + expf(-v));
  }
  float accw[16], accb[16];
#pragma unroll
  for (int i = 0; i < 16; ++i) { accw[i] = 0.f; accb[i] = 0.f; }
  for (int k = 0; k < NC; k += 2) {
    const float w0 = Ww[(size_t)k * NC + tid];
    const float w1 = Ww[(size_t)(k + 1) * NC + tid];
    const float v0 = Wb[(size_t)k * NC + tid];
    const float v1 = Wb[(size_t)(k + 1) * NC + tid];
#pragma unroll
    for (int i = 0; i < 16; ++i) {
      const float2 a = *reinterpret_cast<const float2*>(&xs[i][k]);
      accw[i] = fmaf(a.x, w0, accw[i]);
      accw[i] = fmaf(a.y, w1, accw[i]);
      accb[i] = fmaf(a.x, v0, accb[i]);
      accb[i] = fmaf(a.y, v1, accb[i]);
    }
  }
  const float bwv = bw[tid], bbv = bb[tid];
  for (int i = 0; i < 16; ++i) {
    const size_t o = ((size_t)be * NT + t0 + i) * NC + tid;
    weights[o] = accw[i] + bwv;
    biases[o] = accb[i] + bbv;
  }
}

// ---------------------------------------------------------------------------
// 16-row tile x (512x512) GEMM helper: xs[16][512] in LDS, thread = column.
// ---------------------------------------------------------------------------
__device__ __forceinline__ void tile_gemm16(const float (*xs)[NC],
                                            const float* __restrict__ W,
                                            int tid, float acc[16]) {
#pragma unroll
  for (int i = 0; i < 16; ++i) acc[i] = 0.f;
  for (int k = 0; k < NC; k += 4) {
    const float w0 = W[(size_t)(k + 0) * NC + tid];
    const float w1 = W[(size_t)(k + 1) * NC + tid];
    const float w2 = W[(size_t)(k + 2) * NC + tid];
    const float w3 = W[(size_t)(k + 3) * NC + tid];
#pragma unroll
    for (int i = 0; i < 16; ++i) {
      const float4 a = *reinterpret_cast<const float4*>(&xs[i][k]);
      acc[i] = fmaf(a.x, w0, acc[i]);
      acc[i] = fmaf(a.y, w1, acc[i]);
      acc[i] = fmaf(a.z, w2, acc[i]);
      acc[i] = fmaf(a.w, w3, acc[i]);
    }
  }
}

// LN (+leaky) stats applied in-place on xs[16][NC]
__device__ __forceinline__ void ln_leaky16(float (*xs)[NC],
                                           const float* __restrict__ g,
                                           const float* __restrict__ bt,
                                           int layer, int tid, float* mu_s,
                                           float* rs_s) {
  const int wave = tid >> 6, lane = tid & 63;
  for (int f = wave; f < 16; f += 8) {
    float s = 0.f, s2 = 0.f;
#pragma unroll
    for (int j = 0; j < 8; ++j) {
      const float v = xs[f][lane + 64 * j];
      s += v;
      s2 = fmaf(v, v, s2);
    }
#pragma unroll
    for (int off = 32; off; off >>= 1) {
      s += __shfl_down(s, off);
      s2 += __shfl_down(s2, off);
    }
    if (lane == 0) {
      const float mu = s * (1.f / NC);
      mu_s[f] = mu;
      rs_s[f] = rsqrtf(s2 * (1.f / NC) - mu * mu + 1e-5f);
    }
  }
  __syncthreads();
  const float gv = g[layer * NC + tid], btv = bt[layer * NC + tid];
#pragma unroll
  for (int i = 0; i < 16; ++i) {
    const float y = (xs[i][tid] - mu_s[i]) * rs_s[i] * gv + btv;
    xs[i][tid] = y > 0.f ? y : 0.2f * y;
  }
  __syncthreads();
}

// ---------------------------------------------------------------------------
// K3: windowed impulse -> mlp_imp -> unit_norm * window-norm -> emb stream.
// ---------------------------------------------------------------------------
__global__ __launch_bounds__(512) void k_imp(
    const float* __restrict__ impulse, const float* __restrict__ Ws,
    const float* __restrict__ bs, const float* __restrict__ g,
    const float* __restrict__ bt, float* __restrict__ embo) {
  __shared__ float xs[16][NC];
  __shared__ float wno[16], mu_s[16], rs_s[16], ono[16];
  const int tid = threadIdx.x;
  const int wave = tid >> 6, lane = tid & 63;
  const int be = blockIdx.x;
  const float* ib = impulse + (size_t)be * NIMP;
  for (int f = 0; f < 16; ++f) {
    const int s = f * 256 + tid;
    xs[f][tid] = (s < NIMP) ? ib[s] : 0.f;
  }
  __syncthreads();
  for (int f = wave; f < 16; f += 8) {
    float s = 0.f;
#pragma unroll
    for (int j = 0; j < 8; ++j) {
      const float v = xs[f][lane + 64 * j];
      s = fmaf(v, v, s);
    }
#pragma unroll
    for (int off = 32; off; off >>= 1) s += __shfl_down(s, off);
    if (lane == 0) wno[f] = sqrtf(s);
  }
  __syncthreads();
  float acc[16];
  for (int layer = 0; layer < 4; ++layer) {
    tile_gemm16(xs, Ws + (size_t)layer * NC * NC, tid, acc);
    __syncthreads();
    const float bv = bs[layer * NC + tid];
#pragma unroll
    for (int i = 0; i < 16; ++i) xs[i][tid] = acc[i] + bv;
    __syncthreads();
    if (layer < 3) ln_leaky16(xs, g, bt, layer, tid, mu_s, rs_s);
  }
  for (int f = wave; f < 16; f += 8) {
    float s = 0.f;
#pragma unroll
    for (int j = 0; j < 8; ++j) {
      const float v = xs[f][lane + 64 * j];
      s = fmaf(v, v, s);
    }
#pragma unroll
    for (int off = 32; off; off >>= 1) s += __shfl_down(s, off);
    if (lane == 0) ono[f] = sqrtf(s);
  }
  __syncthreads();
  for (int f = 0; f < 16; ++f)
    embo[((size_t)be * NF + f) * NC + tid] =
        xs[f][tid] / (ono[f] + EPSN) * wno[f];
}

// ---------------------------------------------------------------------------
// K4: the sequential scan, MFMA edition.
// 32 blocks x 512 threads; 8 seqs/block (MFMA M padded to 16, rows 8..15 = 0).
// Per layer: 16x512x512 GEMM via mfma_f32_16x16x32_bf16; wave w owns output
// cols [w*64, w*64+64). A-tile bf16 in LDS (XOR-swizzled, G4); B-frags
// streamed from pre-swizzled Wmf as coalesced dwordx4. h state stays in the
// thread=channel view (tid = channel, h[8] seq regs).
// ---------------------------------------------------------------------------
__global__ __launch_bounds__(512) void k_scan(
    const float* __restrict__ weights, const float* __restrict__ biases,
    const float* __restrict__ leak, const float* __restrict__ embw,
    const unsigned short* __restrict__ Wmf, const float* __restrict__ bs,
    const float* __restrict__ g, const float* __restrict__ bt,
    float* __restrict__ olb, float* __restrict__ onb) {
  __shared__ __align__(16) unsigned short A_lds[16 * NC];  // bf16 A-tile, 16KB
  __shared__ float ol_lds[SPB][NC];                        // 16KB
  __shared__ float red[8][8];
  __shared__ float s_out[8];
  __shared__ float st1[8][8], st2[8][8];  // [wave][row]
  __shared__ float mu_s[8], rs_s[8], cn_s[8], on_s[8], sc_s[8];

  const int tid = threadIdx.x;
  const int wave = tid >> 6, lane = tid & 63;
  const int seq0 = blockIdx.x * SPB;

  // zero the pad rows 8..15 of A (never written again)
  {
    unsigned* z = (unsigned*)(A_lds + 8 * NC);
    for (int i = tid; i < 8 * NC / 2; i += 512) z[i] = 0u;
  }

  // per-lane MFMA geometry
  const int arow = lane & 15;   // A-frag row
  const int kgrp = lane >> 4;   // k-group 0..3
  const int r0 = kgrp * 4;      // C/D row base (row = r0 + reg)
  const bool crow_ok = (r0 < SPB);
  const int abase = arow * (NC * 2);      // A row byte base
  const int axor = (arow & 7) << 4;       // bank swizzle
  const int akoff = kgrp * 16;            // byte offset within k-tile

  // hoist per-lane (t-invariant) bias / LN params for this wave's 4 n-tiles
  float bsv[4][4], gv[3][4], btv[3][4];
#pragma unroll
  for (int p = 0; p < 4; ++p) {
    const int cp = wave * 64 + p * 16 + (lane & 15);
#pragma unroll
    for (int l = 0; l < 4; ++l) bsv[l][p] = bs[l * NC + cp];
#pragma unroll
    for (int l = 0; l < 3; ++l) {
      gv[l][p] = g[l * NC + cp];
      btv[l][p] = bt[l * NC + cp];
    }
  }
  // B-frag base for this wave/lane: element offset of (layer=0, p=0, kt=0)
  const unsigned short* wbase =
      Wmf + ((size_t)(wave * 4) * 16 * 64 + lane) * 8;
  // offsets: +layer*262144 +p*8192 +kt*512 elements

  __syncthreads();

  float h[SPB];
#pragma unroll
  for (int r = 0; r < SPB; ++r) h[r] = 0.f;
  float v[8];

  for (int t = 0; t < NT; ++t) {
    // ---- h += e ----
    if (t < NF) {
#pragma unroll
      for (int r = 0; r < SPB; ++r)
        h[r] += embw[((size_t)(seq0 + r) * NF + t) * NC + tid];
    }
    // ---- cn = ||h|| ----
#pragma unroll
    for (int r = 0; r < SPB; ++r) v[r] = h[r] * h[r];
    blk_reduce<8>(v, s_out, red);
    float cn[SPB];
#pragma unroll
    for (int r = 0; r < SPB; ++r) cn[r] = sqrtf(s_out[r]);
    if (tid == 0) {
#pragma unroll
      for (int r = 0; r < SPB; ++r) cn_s[r] = cn[r];
    }
    // ---- h = unit_norm(h*w + b) * cn ----
    float hw[SPB];
#pragma unroll
    for (int r = 0; r < SPB; ++r) {
      const size_t o = ((size_t)(seq0 + r) * NT + t) * NC + tid;
      hw[r] = fmaf(h[r], weights[o], biases[o]);
      v[r] = hw[r] * hw[r];
    }
    blk_reduce<8>(v, s_out, red);
#pragma unroll
    for (int r = 0; r < SPB; ++r)
      h[r] = hw[r] * (cn[r] / (sqrtf(s_out[r]) + EPSN));
    // ---- pack x -> A_lds rows 0..7 (bf16, swizzled) ----
    {
      char* ab = (char*)A_lds;
#pragma unroll
      for (int r = 0; r < SPB; ++r)
        *(unsigned short*)(ab + r * 1024 + ((tid * 2) ^ ((r & 7) << 4))) =
            f2bf(h[r]);
    }
    __syncthreads();

    // ---- 3 hidden layers (MFMA + LN + leaky) ----
#pragma unroll
    for (int layer = 0; layer < 3; ++layer) {
      f32x4 acc[4];
#pragma unroll
      for (int p = 0; p < 4; ++p) acc[p] = (f32x4){0.f, 0.f, 0.f, 0.f};
      const unsigned short* wl = wbase + (size_t)layer * 262144;
#pragma unroll
      for (int kt = 0; kt < 16; ++kt) {
        const short8v a = *(const short8v*)((const char*)A_lds + abase +
                                            ((kt * 64 + akoff) ^ axor));
#pragma unroll
        for (int p = 0; p < 4; ++p) {
          const short8v b = *(const short8v*)(wl + p * 8192 + kt * 512);
          acc[p] =
              __builtin_amdgcn_mfma_f32_16x16x32_bf16(a, b, acc[p], 0, 0, 0);
        }
      }
      // add bias; per-lane LN partials over this lane's 4 cols
      float s1[4], s2[4];
#pragma unroll
      for (int q = 0; q < 4; ++q) { s1[q] = 0.f; s2[q] = 0.f; }
#pragma unroll
      for (int p = 0; p < 4; ++p) {
#pragma unroll
        for (int q = 0; q < 4; ++q) {
          const float y = acc[p][q] + bsv[layer][p];
          acc[p][q] = y;
          s1[q] += y;
          s2[q] = fmaf(y, y, s2[q]);
        }
      }
      // reduce across the 16 lanes sharing rows
#pragma unroll
      for (int off = 1; off < 16; off <<= 1) {
#pragma unroll
        for (int q = 0; q < 4; ++q) {
          s1[q] += __shfl_xor(s1[q], off);
          s2[q] += __shfl_xor(s2[q], off);
        }
      }
      if ((lane & 15) == 0 && crow_ok) {
#pragma unroll
        for (int q = 0; q < 4; ++q) {
          st1[wave][r0 + q] = s1[q];
          st2[wave][r0 + q] = s2[q];
        }
      }
      __syncthreads();
      if (tid < SPB) {
        float a1 = 0.f, a2 = 0.f;
#pragma unroll
        for (int w = 0; w < 8; ++w) {
          a1 += st1[w][tid];
          a2 += st2[w][tid];
        }
        const float mu = a1 * (1.f / NC);
        mu_s[tid] = mu;
        rs_s[tid] = rsqrtf(a2 * (1.f / NC) - mu * mu + 1e-5f);
      }
      __syncthreads();
      // apply LN + leaky, write next A (rows 0..7 only)
      if (crow_ok) {
        char* ab = (char*)A_lds;
#pragma unroll
        for (int q = 0; q < 4; ++q) {
          const int row = r0 + q;
          const float mu = mu_s[row], rs = rs_s[row];
#pragma unroll
          for (int p = 0; p < 4; ++p) {
            float y = (acc[p][q] - mu) * rs * gv[layer][p] + btv[layer][p];
            y = y > 0.f ? y : 0.2f * y;
            const int cp = wave * 64 + p * 16 + (lane & 15);
            *(unsigned short*)(ab + row * 1024 +
                               ((cp * 2) ^ ((row & 7) << 4))) = f2bf(y);
          }
        }
      }
      __syncthreads();
    }

    // ---- final linear -> ol; epilogue ----
    {
      f32x4 acc[4];
#pragma unroll
      for (int p = 0; p < 4; ++p) acc[p] = (f32x4){0.f, 0.f, 0.f, 0.f};
      const unsigned short* wl = wbase + (size_t)3 * 262144;
#pragma unroll
      for (int kt = 0; kt < 16; ++kt) {
        const short8v a = *(const short8v*)((const char*)A_lds + abase +
                                            ((kt * 64 + akoff) ^ axor));
#pragma unroll
        for (int p = 0; p < 4; ++p) {
          const short8v b = *(const short8v*)(wl + p * 8192 + kt * 512);
          acc[p] =
              __builtin_amdgcn_mfma_f32_16x16x32_bf16(a, b, acc[p], 0, 0, 0);
        }
      }
      float s2[4];
#pragma unroll
      for (int q = 0; q < 4; ++q) s2[q] = 0.f;
#pragma unroll
      for (int p = 0; p < 4; ++p) {
#pragma unroll
        for (int q = 0; q < 4; ++q) {
          const float y = acc[p][q] + bsv[3][p];
          acc[p][q] = y;
          s2[q] = fmaf(y, y, s2[q]);
        }
      }
#pragma unroll
      for (int off = 1; off < 16; off <<= 1) {
#pragma unroll
        for (int q = 0; q < 4; ++q) s2[q] += __shfl_xor(s2[q], off);
      }
      if ((lane & 15) == 0 && crow_ok) {
#pragma unroll
        for (int q = 0; q < 4; ++q) st2[wave][r0 + q] = s2[q];
      }
      if (crow_ok) {
#pragma unroll
        for (int q = 0; q < 4; ++q) {
#pragma unroll
          for (int p = 0; p < 4; ++p)
            ol_lds[r0 + q][wave * 64 + p * 16 + (lane & 15)] = acc[p][q];
        }
      }
      __syncthreads();
      if (tid < SPB) {
        float a2 = 0.f;
#pragma unroll
        for (int w = 0; w < 8; ++w) a2 += st2[w][tid];
        const float no = sqrtf(a2);
        const float lk = leak[(size_t)(seq0 + tid) * NT + t];
        const float sc = cn_s[tid] * lk / (no + EPSN);
        sc_s[tid] = sc;
        const float onv = no * sc;
        on_s[tid] = onv;
        onb[(size_t)(seq0 + tid) * NT + t] = onv;
      }
      __syncthreads();
#pragma unroll
      for (int r = 0; r < SPB; ++r) {
        const float olv = ol_lds[r][tid] * sc_s[r];
        olb[((size_t)(seq0 + r) * NT + t) * NC + tid] = olv;
        h[r] -= olv;
        v[r] = h[r] * h[r];
      }
      blk_reduce<8>(v, s_out, red);
#pragma unroll
      for (int r = 0; r < SPB; ++r)
        h[r] *= (cn[r] - on_s[r]) / (sqrtf(s_out[r]) + EPSN);
    }
  }
}

// ---------------------------------------------------------------------------
// K5: batched out-MLP on all 32768 ol rows: of = unit_norm(mlp_out(ol)*ham)*on
// ---------------------------------------------------------------------------
__global__ __launch_bounds__(512) void k_out(
    const float* __restrict__ olb, const float* __restrict__ onb,
    const float* __restrict__ Ws, const float* __restrict__ bs,
    const float* __restrict__ g, const float* __restrict__ bt,
    float* __restrict__ ofb) {
  __shared__ float xs[16][NC];
  __shared__ float mu_s[16], rs_s[16], ono[16];
  const int tid = threadIdx.x;
  const int wave = tid >> 6, lane = tid & 63;
  const int m0 = blockIdx.x * 16;
  for (int i = 0; i < 16; ++i)
    xs[i][tid] = olb[(size_t)(m0 + i) * NC + tid];
  __syncthreads();
  float acc[16];
  for (int layer = 0; layer < 4; ++layer) {
    tile_gemm16(xs, Ws + (size_t)layer * NC * NC, tid, acc);
    __syncthreads();
    const float bv = bs[layer * NC + tid];
#pragma unroll
    for (int i = 0; i < 16; ++i) xs[i][tid] = acc[i] + bv;
    __syncthreads();
    if (layer < 3) ln_leaky16(xs, g, bt, layer, tid, mu_s, rs_s);
  }
  const float ham =
      0.54f - 0.46f * cosf(6.283185307179586f * (float)tid / (float)NC);
#pragma unroll
  for (int i = 0; i < 16; ++i) xs[i][tid] *= ham;
  __syncthreads();
  for (int f = wave; f < 16; f += 8) {
    float s = 0.f;
#pragma unroll
    for (int j = 0; j < 8; ++j) {
      const float vv = xs[f][lane + 64 * j];
      s = fmaf(vv, vv, s);
    }
#pragma unroll
    for (int off = 32; off; off >>= 1) s += __shfl_down(s, off);
    if (lane == 0) ono[f] = sqrtf(s);
  }
  __syncthreads();
  for (int i = 0; i < 16; ++i) {
    const float onv = onb[m0 + i];
    ofb[(size_t)(m0 + i) * NC + tid] = xs[i][tid] / (ono[i] + EPSN) * onv;
  }
}

// ---------------------------------------------------------------------------
// K6: overlap-add at hop 256, trim to 32768.
// ---------------------------------------------------------------------------
__global__ __launch_bounds__(256) void k_oa(const float* __restrict__ ofb,
                                            float* __restrict__ out) {
  const int idx = blockIdx.x * 256 + threadIdx.x;
  if (idx >= BE * 32768) return;
  const int be = idx >> 15;
  const int s = idx & 32767;
  const int t1 = s >> 8;
  float v = ofb[((size_t)be * NT + t1) * NC + (s - (t1 << 8))];
  if (t1 >= 1)
    v += ofb[((size_t)be * NT + (t1 - 1)) * NC + (s - ((t1 - 1) << 8))];
  out[idx] = v;
}

// ---------------------------------------------------------------------------
// Workspace (< 256 MiB):
//   region A: deform -> olb      16,777,216 f (64 MiB)
//   region B: weights -> ofb     16,777,216 f (64 MiB)
//   region C: biases             16,777,216 f (64 MiB)
//   leakb 32,768 f; embw 2,097,152 f; onb 32,768 f; Wmf 2,097,152 us (4 MiB)
//   total ~204 MiB
// ---------------------------------------------------------------------------
extern "C" void kernel_launch(void* const* d_in, const int* in_sizes, int n_in,
                              void* d_out, int out_size, void* d_ws,
                              size_t ws_size, hipStream_t stream) {
  const float* embedding = (const float*)d_in[0];
  const float* impulse = (const float*)d_in[1];
  const float* W_def = (const float*)d_in[2];
  const float* b_def = (const float*)d_in[3];
  const float* W_w = (const float*)d_in[4];
  const float* b_w = (const float*)d_in[5];
  const float* W_b = (const float*)d_in[6];
  const float* b_b = (const float*)d_in[7];
  const float* W_l = (const float*)d_in[8];
  const float* b_l = (const float*)d_in[9];
  const float* Ws_imp = (const float*)d_in[10];
  const float* bs_imp = (const float*)d_in[11];
  const float* g_imp = (const float*)d_in[12];
  const float* bt_imp = (const float*)d_in[13];
  const float* Ws_lat = (const float*)d_in[14];
  const float* bs_lat = (const float*)d_in[15];
  const float* g_lat = (const float*)d_in[16];
  const float* bt_lat = (const float*)d_in[17];
  const float* Ws_out = (const float*)d_in[18];
  const float* bs_out = (const float*)d_in[19];
  const float* g_out = (const float*)d_in[20];
  const float* bt_out = (const float*)d_in[21];
  float* out = (float*)d_out;

  float* ws = (float*)d_ws;
  float* deform = ws;                  // region A (reused as olb)
  float* weights = deform + 16777216;  // region B (reused as ofb)
  float* biases = weights + 16777216;  // region C
  float* leakb = biases + 16777216;    // 32,768 f
  float* embw = leakb + 32768;         // 2,097,152 f
  float* onb = embw + 2097152;         // 32,768 f
  unsigned short* wmf = (unsigned short*)(onb + 32768);  // 2,097,152 us
  float* olb = deform;                 // alias: deform dead after k_wb
  float* ofb = weights;                // alias: weights dead after k_scan

  k_cvt<<<2048, 64, 0, stream>>>(Ws_lat, wmf);
  k_deform<<<dim3(256, 8), 256, 0, stream>>>(embedding, W_def, b_def, deform);
  k_wb<<<2048, 512, 0, stream>>>(deform, W_w, b_w, W_b, b_b, W_l, b_l,
                                 weights, biases, leakb);
  k_imp<<<256, 512, 0, stream>>>(impulse, Ws_imp, bs_imp, g_imp, bt_imp, embw);
  k_scan<<<NSCAN, 512, 0, stream>>>(weights, biases, leakb, embw, wmf, bs_lat,
                                    g_lat, bt_lat, olb, onb);
  k_out<<<2048, 512, 0, stream>>>(olb, onb, Ws_out, bs_out, g_out, bt_out,
                                  ofb);
  k_oa<<<32768, 256, 0, stream>>>(ofb, out);
}